// Round 4
// baseline (446.927 us; speedup 1.0000x reference)
//
#include <hip/hip_runtime.h>
#include <hip/hip_cooperative_groups.h>

namespace cg = cooperative_groups;

#define D_MODEL 512
#define P_DIM 64
#define C_DIM 32
#define B_DIM 32
#define N_PATCH 2048   // C_DIM * P_DIM
#define SELECT_N 256
#define GRID_BLKS 512  // 2 (b,c) tiles per block in phases A/C; coop-safe at 2 blocks/CU

// Shared memory reused across the three phases (max 17,156 B):
struct SmemA { float wl[D_MODEL]; float red[16][16][4]; };                  // 6,144 B
struct SmemC { float tile[64][65]; int plist[64]; int ilist[64]; int mcnt; };// 17,156 B
union __align__(16) Smem {
  SmemA a;
  unsigned long long key[N_PATCH];  // 16,384 B (sort)
  SmemC c;
};

// ---------------------------------------------------------------------------
// Fused: phase A scores -> grid sync -> phase B per-batch bitonic top-k ->
// grid sync -> phase C inverted gather. Key = (monotone_bits<<32)|(2047-idx)
// gives exact jax.lax.top_k order (ties -> lower idx). Bias unused: constant
// shift doesn't change selection; output is raw x values (bit-exact).
// ---------------------------------------------------------------------------
__global__ __launch_bounds__(256, 2) void fused_kernel(
    const float* __restrict__ x, const float* __restrict__ w,
    float* __restrict__ scores, int* __restrict__ topk,
    float* __restrict__ out) {
  __shared__ Smem sm;
  const int g   = blockIdx.x;
  const int tid = threadIdx.x;   // 256 threads

  // ------------------------- Phase A: scores ------------------------------
  {
    for (int j = tid; j < D_MODEL; j += 256) sm.a.wl[j] = w[j];
    __syncthreads();

    const int pg    = tid & 15;     // float4 group over p
    const int slice = tid >> 4;     // 32-wide d slice

    for (int tt = 0; tt < 2; ++tt) {
      const int bc = g + tt * GRID_BLKS;          // b*32 + c
      const float* base = x + (size_t)bc * D_MODEL * P_DIM + pg * 4;
      float4 acc = make_float4(0.f, 0.f, 0.f, 0.f);
#pragma unroll 8
      for (int dd = 0; dd < 32; ++dd) {
        const int d = slice * 32 + dd;
        const float wd = sm.a.wl[d];
        const float4 v = *(const float4*)(base + (size_t)d * P_DIM);
        acc.x += v.x * wd; acc.y += v.y * wd;
        acc.z += v.z * wd; acc.w += v.w * wd;
      }
      sm.a.red[slice][pg][0] = acc.x; sm.a.red[slice][pg][1] = acc.y;
      sm.a.red[slice][pg][2] = acc.z; sm.a.red[slice][pg][3] = acc.w;
      __syncthreads();
      if (tid < 16) {
        float s0 = 0.f, s1 = 0.f, s2 = 0.f, s3 = 0.f;
#pragma unroll
        for (int k = 0; k < 16; ++k) {
          s0 += sm.a.red[k][tid][0]; s1 += sm.a.red[k][tid][1];
          s2 += sm.a.red[k][tid][2]; s3 += sm.a.red[k][tid][3];
        }
        float* sc = scores + (size_t)bc * P_DIM + tid * 4;
        sc[0] = s0; sc[1] = s1; sc[2] = s2; sc[3] = s3;
      }
      __syncthreads();
    }
  }
  __threadfence();
  cg::this_grid().sync();

  // ------------------------- Phase B: top-k sort --------------------------
  if (g < B_DIM) {
    const int b = g;
    unsigned long long e[8];
    {
      const float4 sA = *(const float4*)(scores + (size_t)b * N_PATCH + 8 * tid);
      const float4 sB = *(const float4*)(scores + (size_t)b * N_PATCH + 8 * tid + 4);
      const float sv[8] = {sA.x, sA.y, sA.z, sA.w, sB.x, sB.y, sB.z, sB.w};
#pragma unroll
      for (int r = 0; r < 8; ++r) {
        unsigned u = __float_as_uint(sv[r]);
        u ^= (u & 0x80000000u) ? 0xFFFFFFFFu : 0x80000000u;
        e[r] = ((unsigned long long)u << 32) |
               (unsigned)(N_PATCH - 1 - (8 * tid + r));
      }
    }

    auto cmpsel = [](unsigned long long& xx, unsigned long long& yy, bool desc) {
      const unsigned long long mx = xx > yy ? xx : yy;
      const unsigned long long mn = xx > yy ? yy : xx;
      xx = desc ? mx : mn; yy = desc ? mn : mx;
    };
    // intra-thread CE, j in {1,2,4}
    auto intra = [&](int j, int k) {
#pragma unroll
      for (int r = 0; r < 8; ++r)
        if ((r & j) == 0) {
          const bool desc = (((8 * tid + r) & k) == 0);
          cmpsel(e[r], e[r | j], desc);
        }
    };
    // cross-lane CE, j in {8..256}: partner lane tid ^ (j/8), k >= 16
    auto xl = [&](int j, int k) {
      const int lj = j >> 3;
      const bool lower = (tid & lj) == 0;
      const bool desc  = ((8 * tid & k) == 0);
      const bool keepmax = (lower == desc);
#pragma unroll
      for (int r = 0; r < 8; ++r) {
        const unsigned long long p = __shfl_xor(e[r], lj, 64);
        e[r] = keepmax ? (e[r] > p ? e[r] : p) : (e[r] < p ? e[r] : p);
      }
    };
    // LDS CE phase for j in {512,1024}; disjoint pair partition, no inner race
    auto ldsp = [&](int j, int k) {
#pragma unroll
      for (int q = 0; q < 8; ++q) {
        const int i = tid + q * 256;
        if ((i & j) == 0) {
          const bool desc = ((i & k) == 0);
          const unsigned long long A = sm.key[i];
          const unsigned long long B = sm.key[i | j];
          if (desc ? (B > A) : (B < A)) { sm.key[i] = B; sm.key[i | j] = A; }
        }
      }
    };

    // Stages k = 2..512: fully register/wave-local.
#pragma unroll
    for (int kk = 1; kk <= 9; ++kk) {
      const int k = 1 << kk;
      for (int j = k >> 1; j >= 8; j >>= 1) xl(j, k);
      for (int j = (k > 8 ? 4 : (k >> 1)); j >= 1; j >>= 1) intra(j, k);
    }
#pragma unroll
    for (int r = 0; r < 8; ++r) sm.key[8 * tid + r] = e[r];
    __syncthreads();

    // Stage k = 1024: j=512 in LDS, tail in regs.
    ldsp(512, 1024);
    __syncthreads();
#pragma unroll
    for (int r = 0; r < 8; ++r) e[r] = sm.key[8 * tid + r];
    for (int j = 256; j >= 8; j >>= 1) xl(j, 1024);
    for (int j = 4; j >= 1; j >>= 1) intra(j, 1024);
#pragma unroll
    for (int r = 0; r < 8; ++r) sm.key[8 * tid + r] = e[r];
    __syncthreads();

    // Stage k = 2048: j=1024,512 in LDS, tail in regs (desc everywhere).
    ldsp(1024, 2048);
    __syncthreads();
    ldsp(512, 2048);
    __syncthreads();
#pragma unroll
    for (int r = 0; r < 8; ++r) e[r] = sm.key[8 * tid + r];
    for (int j = 256; j >= 8; j >>= 1) xl(j, 2048);
    for (int j = 4; j >= 1; j >>= 1) intra(j, 2048);

    if (tid < 32) {
#pragma unroll
      for (int r = 0; r < 8; ++r)
        topk[b * SELECT_N + 8 * tid + r] =
            (N_PATCH - 1) - (int)(e[r] & 0xFFFFFFFFu);
    }
  }
  __threadfence();
  cg::this_grid().sync();

  // ------------------------- Phase C: gather ------------------------------
  {
    const int p4 = (tid & 15) * 4;  // float4 column within row
    const int r0 = tid >> 4;        // row within 16-row group
    const int jr = tid >> 6;        // wave id -> patch group
    const int dd = tid & 63;        // lane -> d offset

    for (int tt = 0; tt < 2; ++tt) {
      const int bc = g + tt * GRID_BLKS;   // same tile this block streamed in A
      const int b  = bc >> 5;
      const int c  = bc & 31;

      if (tid == 0) sm.c.mcnt = 0;
      __syncthreads();
      {
        const int n = topk[b * SELECT_N + tid];
        if ((n >> 6) == c) {
          const int slot = atomicAdd(&sm.c.mcnt, 1);
          sm.c.plist[slot] = n & 63;
          sm.c.ilist[slot] = tid;
        }
      }
      __syncthreads();
      const int m = sm.c.mcnt;
      if (m > 0) {
        const float* xb = x + (size_t)bc * (D_MODEL * P_DIM);
        for (int d0 = 0; d0 < D_MODEL; d0 += 64) {
#pragma unroll
          for (int q = 0; q < 4; ++q) {
            const int drow = r0 + q * 16;
            const float4 v =
                *(const float4*)(xb + (size_t)(d0 + drow) * P_DIM + p4);
            sm.c.tile[drow][p4]     = v.x;
            sm.c.tile[drow][p4 + 1] = v.y;
            sm.c.tile[drow][p4 + 2] = v.z;
            sm.c.tile[drow][p4 + 3] = v.w;
          }
          __syncthreads();
          for (int j = jr; j < m; j += 4) {
            out[(size_t)(b * SELECT_N + sm.c.ilist[j]) * D_MODEL + d0 + dd] =
                sm.c.tile[dd][sm.c.plist[j]];
          }
          __syncthreads();
        }
      }
    }
  }
}

extern "C" void kernel_launch(void* const* d_in, const int* in_sizes, int n_in,
                              void* d_out, int out_size, void* d_ws, size_t ws_size,
                              hipStream_t stream) {
  const float* x = (const float*)d_in[0];
  const float* w = (const float*)d_in[1];
  // d_in[2] (bias) intentionally unused: constant shift doesn't change top-k.

  float* scores = (float*)d_ws;                                          // 256 KB
  int*   topk   = (int*)((char*)d_ws + B_DIM * N_PATCH * sizeof(float)); // 32 KB
  float* out    = (float*)d_out;

  void* args[] = {(void*)&x, (void*)&w, (void*)&scores, (void*)&topk, (void*)&out};
  hipLaunchCooperativeKernel((void*)fused_kernel, dim3(GRID_BLKS), dim3(256),
                             args, 0, stream);
}

// Round 5
// 230.700 us; speedup vs baseline: 1.9373x; 1.9373x over previous
//
#include <hip/hip_runtime.h>

#define D_MODEL 512
#define P_DIM 64
#define C_DIM 32
#define B_DIM 32
#define N_PATCH 2048   // C_DIM * P_DIM
#define SELECT_N 256

// ---------------------------------------------------------------------------
// Kernel 1 (v2): scores[b*2048 + c*64 + p] = sum_d x[b,c,d,p] * w[d]
// One block per (b,c). 256 threads: pg = tid&15 (float4 group over p),
// slice = tid>>4, d = slice + 16*i  -->  a wave's 64 lanes cover 4 ADJACENT
// rows x 64 cols = one contiguous 1 KB segment per VMEM instruction
// (vs the old slice*32+dd mapping: 4 segments 8 KB apart, ~1.6 TB/s).
// Bias omitted: constant offset does not affect top-k selection/order.
// ---------------------------------------------------------------------------
__global__ __launch_bounds__(256) void scores_kernel(
    const float* __restrict__ x, const float* __restrict__ w,
    float* __restrict__ scores) {
  __shared__ float wl[D_MODEL];
  __shared__ float4 red[16][16];

  const int bc  = blockIdx.x;      // b*32 + c
  const int tid = threadIdx.x;

  for (int j = tid; j < D_MODEL; j += 256) wl[j] = w[j];
  __syncthreads();

  const int pg    = tid & 15;      // p-group: covers p = 4*pg .. 4*pg+3
  const int slice = tid >> 4;      // 0..15

  const float* base = x + (size_t)bc * D_MODEL * P_DIM + pg * 4;
  float4 acc = make_float4(0.f, 0.f, 0.f, 0.f);
#pragma unroll 8
  for (int i = 0; i < 32; ++i) {
    const int d = slice + 16 * i;          // contiguous per-wave access
    const float wd = wl[d];
    const float4 v = *(const float4*)(base + (size_t)d * P_DIM);
    acc.x += v.x * wd; acc.y += v.y * wd; acc.z += v.z * wd; acc.w += v.w * wd;
  }
  red[slice][pg] = acc;
  __syncthreads();

  if (tid < 16) {
    float4 s = red[0][tid];
#pragma unroll
    for (int k = 1; k < 16; ++k) {
      const float4 t = red[k][tid];
      s.x += t.x; s.y += t.y; s.z += t.z; s.w += t.w;
    }
    float* sc = scores + (size_t)bc * P_DIM + tid * 4;
    sc[0] = s.x; sc[1] = s.y; sc[2] = s.z; sc[3] = s.w;
  }
}

// ---------------------------------------------------------------------------
// Kernel 2: per-batch bitonic sort of 2048 keys, warp-local for j<=64.
// Key = (monotone_float_bits << 32) | (2047 - idx): descending u64 order ==
// descending score with ties -> lower idx (exact jax.lax.top_k semantics).
// ---------------------------------------------------------------------------
__global__ __launch_bounds__(1024) void topk_kernel(
    const float* __restrict__ scores, int* __restrict__ topk) {
  __shared__ unsigned long long key[N_PATCH];
  const int b = blockIdx.x;
  const int t = threadIdx.x;   // 1024 threads

  const float2 s2 = *(const float2*)(scores + (size_t)b * N_PATCH + 2 * t);
  unsigned u0 = __float_as_uint(s2.x);
  unsigned u1 = __float_as_uint(s2.y);
  u0 ^= (u0 & 0x80000000u) ? 0xFFFFFFFFu : 0x80000000u;
  u1 ^= (u1 & 0x80000000u) ? 0xFFFFFFFFu : 0x80000000u;
  unsigned long long e0 =
      ((unsigned long long)u0 << 32) | (unsigned)(N_PATCH - 1 - (2 * t));
  unsigned long long e1 =
      ((unsigned long long)u1 << 32) | (unsigned)(N_PATCH - 1 - (2 * t + 1));

  auto ce_shfl = [&](int j, int k) {
    const bool desc  = ((2 * t) & k) == 0;
    const bool lower = (t & (j >> 1)) == 0;
    const unsigned long long p0 = __shfl_xor(e0, j >> 1, 64);
    const unsigned long long p1 = __shfl_xor(e1, j >> 1, 64);
    const bool keepmax = (lower == desc);
    e0 = keepmax ? (e0 > p0 ? e0 : p0) : (e0 < p0 ? e0 : p0);
    e1 = keepmax ? (e1 > p1 ? e1 : p1) : (e1 < p1 ? e1 : p1);
  };
  auto ce_intra = [&](int k) {
    const bool desc = ((2 * t) & k) == 0;
    const unsigned long long mx = e0 > e1 ? e0 : e1;
    const unsigned long long mn = e0 > e1 ? e1 : e0;
    e0 = desc ? mx : mn;
    e1 = desc ? mn : mx;
  };

#pragma unroll
  for (int kk = 1; kk <= 7; ++kk) {
    const int k = 1 << kk;
    for (int j = k >> 1; j >= 2; j >>= 1) ce_shfl(j, k);
    ce_intra(k);
  }

  key[2 * t] = e0; key[2 * t + 1] = e1;
  __syncthreads();

#pragma unroll
  for (int kk = 8; kk <= 11; ++kk) {
    const int k = 1 << kk;
    for (int j = k >> 1; j >= 128; j >>= 1) {
#pragma unroll
      for (int q = 0; q < 2; ++q) {
        const int i   = t + q * 1024;
        const int ixj = i ^ j;
        if (ixj > i) {
          const bool desc = (i & k) == 0;
          const unsigned long long a = key[i];
          const unsigned long long c = key[ixj];
          if (desc ? (c > a) : (c < a)) { key[i] = c; key[ixj] = a; }
        }
      }
      __syncthreads();
    }
    e0 = key[2 * t]; e1 = key[2 * t + 1];
#pragma unroll
    for (int j = 64; j >= 2; j >>= 1) ce_shfl(j, k);
    ce_intra(k);
    if (k < N_PATCH) {
      key[2 * t] = e0; key[2 * t + 1] = e1;
      __syncthreads();
    }
  }

  if (t < 128) {
    topk[b * SELECT_N + 2 * t]     = (N_PATCH - 1) - (int)(e0 & 0xFFFFFFFFu);
    topk[b * SELECT_N + 2 * t + 1] = (N_PATCH - 1) - (int)(e1 & 0xFFFFFFFFu);
  }
}

// ---------------------------------------------------------------------------
// Kernel 3: inverted gather. One block per (b,c). Scan this batch's 256
// topk entries for channel c (avg m~8 hits), stream the whole x[b,c,:,:]
// tile (128 KB, L3-resident after scores pass) through LDS in coalesced
// float4 rows (contiguous 1 KB per wave-instr), write each selected patch
// coalesced over d. LDS padded to 65 -> transpose reads ~2-way = free.
// ---------------------------------------------------------------------------
__global__ __launch_bounds__(256) void gather_kernel(
    const float* __restrict__ x, const int* __restrict__ topk,
    float* __restrict__ out) {
  __shared__ float tile[64][65];
  __shared__ int plist[64];
  __shared__ int ilist[64];
  __shared__ int mcnt;

  const int bc = blockIdx.x;     // b*32 + c
  const int b  = bc >> 5;
  const int c  = bc & 31;
  const int t  = threadIdx.x;    // 256 threads

  if (t == 0) mcnt = 0;
  __syncthreads();

  {
    const int n = topk[b * SELECT_N + t];   // one entry per thread
    if ((n >> 6) == c) {
      const int slot = atomicAdd(&mcnt, 1);
      plist[slot] = n & 63;
      ilist[slot] = t;                       // output rank
    }
  }
  __syncthreads();
  const int m = mcnt;
  if (m == 0) return;

  const float* xb = x + (size_t)bc * (D_MODEL * P_DIM);

  const int p4 = (t & 15) * 4;   // float4 column offset within a row
  const int r0 = t >> 4;         // 0..15: row within 16-row load group
  const int jr = t >> 6;         // 0..3: wave id = patch group for writes
  const int dd = t & 63;         // lane = d offset within chunk for writes

  for (int d0 = 0; d0 < D_MODEL; d0 += 64) {
#pragma unroll
    for (int q = 0; q < 4; ++q) {
      const int drow = r0 + q * 16;
      const float4 v =
          *(const float4*)(xb + (size_t)(d0 + drow) * P_DIM + p4);
      tile[drow][p4]     = v.x;
      tile[drow][p4 + 1] = v.y;
      tile[drow][p4 + 2] = v.z;
      tile[drow][p4 + 3] = v.w;
    }
    __syncthreads();
    for (int j = jr; j < m; j += 4) {
      out[(size_t)(b * SELECT_N + ilist[j]) * D_MODEL + d0 + dd] =
          tile[dd][plist[j]];
    }
    __syncthreads();
  }
}

extern "C" void kernel_launch(void* const* d_in, const int* in_sizes, int n_in,
                              void* d_out, int out_size, void* d_ws, size_t ws_size,
                              hipStream_t stream) {
  const float* x = (const float*)d_in[0];
  const float* w = (const float*)d_in[1];
  // d_in[2] (bias) intentionally unused: constant shift doesn't change top-k.

  float* scores = (float*)d_ws;                                          // 256 KB
  int*   topk   = (int*)((char*)d_ws + B_DIM * N_PATCH * sizeof(float)); // 32 KB
  float* out    = (float*)d_out;

  scores_kernel<<<B_DIM * C_DIM, 256, 0, stream>>>(x, w, scores);
  topk_kernel<<<B_DIM, 1024, 0, stream>>>(scores, topk);
  gather_kernel<<<B_DIM * C_DIM, 256, 0, stream>>>(x, topk, out);
}